// Round 1
// baseline (8922.745 us; speedup 1.0000x reference)
//
#include <hip/hip_runtime.h>

#define B_   1024
#define TE   168
#define TD   24
#define F_   64
#define H_   128
#define H2_  256
#define G_   512

// ---- workspace float offsets ----
#define OFF_WeT    0          // [256][128]
#define OFF_WiT    32768      // [64][128]
#define OFF_VdT    40960      // [128][64]
#define OFF_eWihT  49152      // [64][512]
#define OFF_eWhhT  81920      // [128][512]
#define OFF_mWihT  147456     // [128][512]
#define OFF_mWhhT  212992     // [128][512]
#define OFF_WxT    278528     // [128][128]
#define OFF_WhT    294912     // [256][128]
#define OFF_dWihT  327680     // [128][512]
#define OFF_dWhhT  393216     // [128][512]
#define OFF_ENCB   458752     // [512] bih+bhh
#define OFF_MIDB   459264
#define OFF_DECB   459776
#define OFF_MID    460800                      // [1024][168][128]
#define OFF_WX     (OFF_MID + B_*TE*H_)        // [1024][168][128]
#define OFF_STH    (OFF_WX  + B_*TE*H_)        // [1024][128]
#define OFF_STC    (OFF_STH + B_*H_)
#define WS_FLOATS  (OFF_STC + B_*H_)

__device__ __forceinline__ float fexp2(float x) { return __builtin_amdgcn_exp2f(x); }
__device__ __forceinline__ float frcp(float x)  { return __builtin_amdgcn_rcpf(x); }
#define LOG2E 1.4426950408889634f

__device__ __forceinline__ float sigm(float x) {
    // 1/(1+e^-x)
    return frcp(1.f + fexp2(-LOG2E * x));
}
__device__ __forceinline__ float tanh_fast(float x) {
    // tanh(x) = 1 - 2/(e^{2x}+1); exp2/rcp are ~1ulp HW ops
    float e = fexp2(2.f * LOG2E * x);
    return 1.f - 2.f * frcp(e + 1.f);
}

// ---------------- prep: transpose weights to [K][N], sum bias pairs ----------------
struct PrepArgs {
    const float *We, *Wi, *Vd, *eWih, *eWhh, *eBih, *eBhh,
                *mWih, *mWhh, *mBih, *mBhh, *Wx, *Wh, *dWih, *dWhh, *dBih, *dBhh;
};

__global__ void prep_kernel(PrepArgs a, float* __restrict__ ws) {
    int sec  = blockIdx.x >> 2;
    int base = (blockIdx.x & 3) * blockDim.x + threadIdx.x;
    const int stride = blockDim.x * 4;
    const float* src = nullptr; int R = 0, C = 0, off = 0;
    switch (sec) {
        case 0:  src = a.We;   R = 128; C = 256; off = OFF_WeT;   break;
        case 1:  src = a.Wi;   R = 128; C = 64;  off = OFF_WiT;   break;
        case 2:  src = a.Vd;   R = 64;  C = 128; off = OFF_VdT;   break;
        case 3:  src = a.eWih; R = 512; C = 64;  off = OFF_eWihT; break;
        case 4:  src = a.eWhh; R = 512; C = 128; off = OFF_eWhhT; break;
        case 5:  src = a.mWih; R = 512; C = 128; off = OFF_mWihT; break;
        case 6:  src = a.mWhh; R = 512; C = 128; off = OFF_mWhhT; break;
        case 7:  src = a.Wx;   R = 128; C = 128; off = OFF_WxT;   break;
        case 8:  src = a.Wh;   R = 128; C = 256; off = OFF_WhT;   break;
        case 9:  src = a.dWih; R = 512; C = 128; off = OFF_dWihT; break;
        case 10: src = a.dWhh; R = 512; C = 128; off = OFF_dWhhT; break;
        case 11: for (int i = base; i < 512; i += stride) ws[OFF_ENCB + i] = a.eBih[i] + a.eBhh[i]; return;
        case 12: for (int i = base; i < 512; i += stride) ws[OFF_MIDB + i] = a.mBih[i] + a.mBhh[i]; return;
        case 13: for (int i = base; i < 512; i += stride) ws[OFF_DECB + i] = a.dBih[i] + a.dBhh[i]; return;
        default: return;
    }
    int n = R * C;
    int rmask  = R - 1;
    int rshift = (R == 512) ? 9 : ((R == 128) ? 7 : 6);
    // dst[c*R + r] = src[r*C + c]  (dst layout [C][R] = W^T as [K][N])
    for (int o = base; o < n; o += stride) {
        int r = o & rmask, c = o >> rshift;
        ws[off + o] = src[r * C + c];
    }
}

// ---------------- persistent encoder + mid LSTM: 128 blocks x 512 thr, 8 rows/block ----------------
__global__ __launch_bounds__(512, 1) void enc_mid_kernel(
    const float* __restrict__ x_all,   // [B][Te][F]
    const float* __restrict__ Wi_b,
    const float* __restrict__ Vd_b,
    const float* __restrict__ Wx_b,
    float* __restrict__ ws)
{
    __shared__ float hc[8][H2_];      // [h | c] encoder state
    __shared__ float hm[8][H_];       // mid h
    __shared__ float cm[8][H_];       // mid c
    __shared__ float xt[8][F_];
    __shared__ float xin[8][F_];
    __shared__ float av[8][H_];       // tanh activation before Vd
    __shared__ float gt[8][G_];       // gate scratch
    __shared__ float bWi[H_], bVd[F_], bWx[H_];
    __shared__ float bE[G_], bM[G_];

    const int tid = threadIdx.x;
    const int b0  = blockIdx.x * 8;

    for (int i = tid; i < 8 * H2_; i += 512) ((float*)hc)[i] = 0.f;
    for (int i = tid; i < 8 * H_;  i += 512) { ((float*)hm)[i] = 0.f; ((float*)cm)[i] = 0.f; }
    if (tid < H_) { bWi[tid] = Wi_b[tid]; bWx[tid] = Wx_b[tid]; }
    if (tid < F_) bVd[tid] = Vd_b[tid];
    if (tid < G_) { bE[tid] = ws[OFF_ENCB + tid]; bM[tid] = ws[OFF_MIDB + tid]; }
    __syncthreads();

    const float4* WeT4   = (const float4*)(ws + OFF_WeT);     // [256][128]
    const float4* WiT4   = (const float4*)(ws + OFF_WiT);     // [64][128]
    const float*  VdT    = ws + OFF_VdT;                      // [128][64]
    const float4* eWihT4 = (const float4*)(ws + OFF_eWihT);   // [64][512]
    const float4* eWhhT4 = (const float4*)(ws + OFF_eWhhT);   // [128][512]
    const float4* mWihT4 = (const float4*)(ws + OFF_mWihT);   // [128][512]
    const float4* mWhhT4 = (const float4*)(ws + OFF_mWhhT);   // [128][512]
    const float4* WxT4   = (const float4*)(ws + OFF_WxT);     // [128][128]
    float* mid_out = ws + OFF_MID;
    float* wx_out  = ws + OFF_WX;

    for (int t = 0; t < TE; ++t) {
        { // load x_t : 8 x 64 by 512 threads
            int r = tid >> 6, f = tid & 63;
            xt[r][f] = x_all[((b0 + r) * TE + t) * F_ + f];
        }
        __syncthreads();

        // m1: av = tanh([h|c]@WeT + x@WiT + bWi)  [8][128]
        if (tid < 256) {
            int cg = tid & 31, r = tid >> 5;
            int j0 = cg * 4;
            float a0 = bWi[j0], a1 = bWi[j0+1], a2 = bWi[j0+2], a3 = bWi[j0+3];
            #pragma unroll 4
            for (int k = 0; k < H2_; ++k) {
                float4 w = WeT4[k * 32 + cg];
                float h = hc[r][k];
                a0 += w.x * h; a1 += w.y * h; a2 += w.z * h; a3 += w.w * h;
            }
            #pragma unroll 4
            for (int k = 0; k < F_; ++k) {
                float4 w = WiT4[k * 32 + cg];
                float xv = xt[r][k];
                a0 += w.x * xv; a1 += w.y * xv; a2 += w.z * xv; a3 += w.w * xv;
            }
            av[r][j0]   = tanh_fast(a0); av[r][j0+1] = tanh_fast(a1);
            av[r][j0+2] = tanh_fast(a2); av[r][j0+3] = tanh_fast(a3);
        }
        __syncthreads();

        // m2: s = av@VdT + bVd ; softmax over 64 (one wave per row); xin = xt * softmax(s)
        {
            int j = tid & 63, r = tid >> 6;   // wave r handles row r
            float acc = bVd[j];
            #pragma unroll 8
            for (int k = 0; k < H_; ++k)
                acc += VdT[k * 64 + j] * av[r][k];
            float m = acc;
            for (int off = 32; off > 0; off >>= 1) m = fmaxf(m, __shfl_xor(m, off, 64));
            float e = fexp2((acc - m) * LOG2E);
            float ssum = e;
            for (int off = 32; off > 0; off >>= 1) ssum += __shfl_xor(ssum, off, 64);
            xin[r][j] = xt[r][j] * e * frcp(ssum);
        }
        __syncthreads();

        // m3: enc gates [8][512] = xin@eWihT + h@eWhhT + bE
        {
            int cg = tid & 127, rg = tid >> 7;
            int r0 = rg * 2, r1 = r0 + 1;
            int j0 = cg * 4;
            float a00 = bE[j0], a01 = bE[j0+1], a02 = bE[j0+2], a03 = bE[j0+3];
            float a10 = a00, a11 = a01, a12 = a02, a13 = a03;
            #pragma unroll 4
            for (int k = 0; k < F_; ++k) {
                float4 w = eWihT4[k * 128 + cg];
                float x0 = xin[r0][k], x1 = xin[r1][k];
                a00 += w.x*x0; a01 += w.y*x0; a02 += w.z*x0; a03 += w.w*x0;
                a10 += w.x*x1; a11 += w.y*x1; a12 += w.z*x1; a13 += w.w*x1;
            }
            #pragma unroll 4
            for (int k = 0; k < H_; ++k) {
                float4 w = eWhhT4[k * 128 + cg];
                float h0 = hc[r0][k], h1 = hc[r1][k];
                a00 += w.x*h0; a01 += w.y*h0; a02 += w.z*h0; a03 += w.w*h0;
                a10 += w.x*h1; a11 += w.y*h1; a12 += w.z*h1; a13 += w.w*h1;
            }
            *(float4*)&gt[r0][j0] = make_float4(a00, a01, a02, a03);
            *(float4*)&gt[r1][j0] = make_float4(a10, a11, a12, a13);
        }
        __syncthreads();

        // enc LSTM cell update
        {
            int j = tid & 127, rg = tid >> 7;
            #pragma unroll
            for (int rr = rg * 2; rr <= rg * 2 + 1; ++rr) {
                float gi = gt[rr][j], gf = gt[rr][j+128], gg = gt[rr][j+256], go = gt[rr][j+384];
                float c = sigm(gf) * hc[rr][H_ + j] + sigm(gi) * tanh_fast(gg);
                float h = sigm(go) * tanh_fast(c);
                hc[rr][H_ + j] = c; hc[rr][j] = h;
            }
        }
        __syncthreads();

        // m5: mid gates [8][512] = h_enc@mWihT + h_mid@mWhhT + bM
        {
            int cg = tid & 127, rg = tid >> 7;
            int r0 = rg * 2, r1 = r0 + 1;
            int j0 = cg * 4;
            float a00 = bM[j0], a01 = bM[j0+1], a02 = bM[j0+2], a03 = bM[j0+3];
            float a10 = a00, a11 = a01, a12 = a02, a13 = a03;
            #pragma unroll 4
            for (int k = 0; k < H_; ++k) {
                float4 w = mWihT4[k * 128 + cg];
                float x0 = hc[r0][k], x1 = hc[r1][k];
                a00 += w.x*x0; a01 += w.y*x0; a02 += w.z*x0; a03 += w.w*x0;
                a10 += w.x*x1; a11 += w.y*x1; a12 += w.z*x1; a13 += w.w*x1;
            }
            #pragma unroll 4
            for (int k = 0; k < H_; ++k) {
                float4 w = mWhhT4[k * 128 + cg];
                float h0 = hm[r0][k], h1 = hm[r1][k];
                a00 += w.x*h0; a01 += w.y*h0; a02 += w.z*h0; a03 += w.w*h0;
                a10 += w.x*h1; a11 += w.y*h1; a12 += w.z*h1; a13 += w.w*h1;
            }
            *(float4*)&gt[r0][j0] = make_float4(a00, a01, a02, a03);
            *(float4*)&gt[r1][j0] = make_float4(a10, a11, a12, a13);
        }
        __syncthreads();

        // mid LSTM cell update + store mid_out
        {
            int j = tid & 127, rg = tid >> 7;
            #pragma unroll
            for (int rr = rg * 2; rr <= rg * 2 + 1; ++rr) {
                float gi = gt[rr][j], gf = gt[rr][j+128], gg = gt[rr][j+256], go = gt[rr][j+384];
                float c = sigm(gf) * cm[rr][j] + sigm(gi) * tanh_fast(gg);
                float h = sigm(go) * tanh_fast(c);
                cm[rr][j] = c; hm[rr][j] = h;
                mid_out[((b0 + rr) * TE + t) * H_ + j] = h;
            }
        }
        __syncthreads();

        // m6: wx[b][t][:] = h_mid@WxT + bWx  [8][128]
        if (tid < 256) {
            int cg = tid & 31, r = tid >> 5;
            int j0 = cg * 4;
            float a0 = bWx[j0], a1 = bWx[j0+1], a2 = bWx[j0+2], a3 = bWx[j0+3];
            #pragma unroll 4
            for (int k = 0; k < H_; ++k) {
                float4 w = WxT4[k * 32 + cg];
                float h = hm[r][k];
                a0 += w.x*h; a1 += w.y*h; a2 += w.z*h; a3 += w.w*h;
            }
            *(float4*)&wx_out[((b0 + r) * TE + t) * H_ + j0] = make_float4(a0, a1, a2, a3);
        }
        __syncthreads();
    }

    // final mid state -> decoder init
    {
        int j = tid & 127, rg = tid >> 7;
        #pragma unroll
        for (int rr = rg * 2; rr <= rg * 2 + 1; ++rr) {
            ws[OFF_STH + (b0 + rr) * H_ + j] = hm[rr][j];
            ws[OFF_STC + (b0 + rr) * H_ + j] = cm[rr][j];
        }
    }
}

// ---------------- persistent decoder: 256 blocks x 256 thr, 4 rows/block ----------------
__global__ __launch_bounds__(256, 1) void dec_kernel(
    const float* __restrict__ Vw_in,   // V_w [1][128]
    const float* __restrict__ Vb_in,   // [1]
    const float* __restrict__ rw_in,   // reg_w [1][128]
    const float* __restrict__ rb_in,   // [1]
    const float* __restrict__ ws,
    float* __restrict__ out)
{
    __shared__ float hc2[4][H2_];      // [hi | ci]
    __shared__ float qv[4][H_];
    __shared__ float sb[4][TE];
    __shared__ float din[2][4][H_];
    __shared__ float gt2[4][G_];
    __shared__ float bD[G_], Vw[H_], rw[H_];

    const int tid = threadIdx.x;
    const int b0  = blockIdx.x * 4;
    const float Vb = Vb_in[0], rb = rb_in[0];

    for (int i = tid; i < 4 * H2_; i += 256) {
        int r = i >> 8, c = i & 255;
        hc2[r][c] = (c < H_) ? ws[OFF_STH + (b0 + r) * H_ + c]
                             : ws[OFF_STC + (b0 + r) * H_ + (c - H_)];
    }
    if (tid < H_) { Vw[tid] = Vw_in[tid]; rw[tid] = rw_in[tid]; }
    for (int i = tid; i < G_; i += 256) bD[i] = ws[OFF_DECB + i];
    __syncthreads();

    const float*  WhT    = ws + OFF_WhT;                      // [256][128]
    const float4* dWihT4 = (const float4*)(ws + OFF_dWihT);   // [128][512]
    const float4* dWhhT4 = (const float4*)(ws + OFF_dWhhT);   // [128][512]
    const float4* wx4    = (const float4*)(ws + OFF_WX);
    const float4* mid4   = (const float4*)(ws + OFF_MID);

    for (int td = 0; td < TD; ++td) {
        // q = [hi|ci]@WhT  [4][128]
        {
            int j = tid & 127, rg = tid >> 7;
            int r0 = rg * 2, r1 = r0 + 1;
            float a0 = 0.f, a1 = 0.f;
            #pragma unroll 4
            for (int k = 0; k < H2_; ++k) {
                float w = WhT[k * H_ + j];
                a0 += w * hc2[r0][k]; a1 += w * hc2[r1][k];
            }
            qv[r0][j] = a0; qv[r1][j] = a1;
        }
        __syncthreads();

        // scores: sb[r][tp] = sum_h tanh(q[r][h] + wx[b][tp][h]) * Vw[h] + Vb
        {
            int r = tid >> 6, lane = tid & 63;
            for (int tp = lane; tp < TE; tp += 64) {
                const float4* wxr = wx4 + ((size_t)(b0 + r) * TE + tp) * (H_ / 4);
                float acc = Vb;
                #pragma unroll 8
                for (int kk = 0; kk < H_ / 4; ++kk) {
                    float4 w = wxr[kk];
                    int j = kk * 4;
                    acc += tanh_fast(qv[r][j]     + w.x) * Vw[j];
                    acc += tanh_fast(qv[r][j + 1] + w.y) * Vw[j + 1];
                    acc += tanh_fast(qv[r][j + 2] + w.z) * Vw[j + 2];
                    acc += tanh_fast(qv[r][j + 3] + w.w) * Vw[j + 3];
                }
                sb[r][tp] = acc;
            }
        }
        __syncthreads();

        // dec_in = sum_tp sb[r][tp] * mid[b][tp][:]  (split tp range in 2)
        {
            int jg = tid & 31, r = (tid >> 5) & 3, ts = tid >> 7;
            int t0 = ts * 84;
            float4 a = make_float4(0.f, 0.f, 0.f, 0.f);
            #pragma unroll 4
            for (int tp = t0; tp < t0 + 84; ++tp) {
                float s = sb[r][tp];
                float4 m = mid4[((size_t)(b0 + r) * TE + tp) * 32 + jg];
                a.x += s * m.x; a.y += s * m.y; a.z += s * m.z; a.w += s * m.w;
            }
            *(float4*)&din[ts][r][jg * 4] = a;
        }
        __syncthreads();
        for (int i = tid; i < 4 * H_; i += 256) {
            int r = i >> 7, j = i & 127;
            din[0][r][j] += din[1][r][j];
        }
        __syncthreads();

        // gates [4][512] = dec_in@dWihT + hi@dWhhT + bD
        {
            int cg = tid & 127, rg = tid >> 7;
            int r0 = rg * 2, r1 = r0 + 1;
            int j0 = cg * 4;
            float a00 = bD[j0], a01 = bD[j0+1], a02 = bD[j0+2], a03 = bD[j0+3];
            float a10 = a00, a11 = a01, a12 = a02, a13 = a03;
            #pragma unroll 4
            for (int k = 0; k < H_; ++k) {
                float4 w = dWihT4[k * 128 + cg];
                float x0 = din[0][r0][k], x1 = din[0][r1][k];
                a00 += w.x*x0; a01 += w.y*x0; a02 += w.z*x0; a03 += w.w*x0;
                a10 += w.x*x1; a11 += w.y*x1; a12 += w.z*x1; a13 += w.w*x1;
            }
            #pragma unroll 4
            for (int k = 0; k < H_; ++k) {
                float4 w = dWhhT4[k * 128 + cg];
                float h0 = hc2[r0][k], h1 = hc2[r1][k];
                a00 += w.x*h0; a01 += w.y*h0; a02 += w.z*h0; a03 += w.w*h0;
                a10 += w.x*h1; a11 += w.y*h1; a12 += w.z*h1; a13 += w.w*h1;
            }
            *(float4*)&gt2[r0][j0] = make_float4(a00, a01, a02, a03);
            *(float4*)&gt2[r1][j0] = make_float4(a10, a11, a12, a13);
        }
        __syncthreads();

        // LSTM update
        {
            int j = tid & 127, rg = tid >> 7;
            #pragma unroll
            for (int rr = rg * 2; rr <= rg * 2 + 1; ++rr) {
                float gi = gt2[rr][j], gf = gt2[rr][j+128], gg = gt2[rr][j+256], go = gt2[rr][j+384];
                float c = sigm(gf) * hc2[rr][H_ + j] + sigm(gi) * tanh_fast(gg);
                float h = sigm(go) * tanh_fast(c);
                hc2[rr][H_ + j] = c; hc2[rr][j] = h;
            }
        }
        __syncthreads();

        // out[b][td] = h . reg_w + reg_b  (one wave per row)
        {
            int r = tid >> 6, lane = tid & 63;
            float v = hc2[r][lane] * rw[lane] + hc2[r][lane + 64] * rw[lane + 64];
            for (int off = 32; off > 0; off >>= 1) v += __shfl_xor(v, off, 64);
            if (lane == 0) out[(b0 + r) * TD + td] = v + rb;
        }
        __syncthreads();
    }
}

extern "C" void kernel_launch(void* const* d_in, const int* in_sizes, int n_in,
                              void* d_out, int out_size, void* d_ws, size_t ws_size,
                              hipStream_t stream)
{
    (void)in_sizes; (void)n_in; (void)out_size;
    if (ws_size < (size_t)WS_FLOATS * sizeof(float)) return;  // workspace too small: fail loudly

    const float* x_all = (const float*)d_in[0];
    const float* Wi_b  = (const float*)d_in[3];
    const float* Vd_b  = (const float*)d_in[6];
    const float* Wx_b  = (const float*)d_in[16];
    const float* V_w   = (const float*)d_in[18];
    const float* V_b   = (const float*)d_in[19];
    const float* reg_w = (const float*)d_in[24];
    const float* reg_b = (const float*)d_in[25];
    float* ws  = (float*)d_ws;
    float* out = (float*)d_out;

    PrepArgs pa{
        (const float*)d_in[4],  // We_w
        (const float*)d_in[2],  // Wi_w
        (const float*)d_in[5],  // Vd_w
        (const float*)d_in[7],  // enc_Wih
        (const float*)d_in[8],  // enc_Whh
        (const float*)d_in[9],  // enc_bih
        (const float*)d_in[10], // enc_bhh
        (const float*)d_in[11], // mid_Wih
        (const float*)d_in[12], // mid_Whh
        (const float*)d_in[13], // mid_bih
        (const float*)d_in[14], // mid_bhh
        (const float*)d_in[15], // Wx_w
        (const float*)d_in[17], // Wh_w
        (const float*)d_in[20], // dec_Wih
        (const float*)d_in[21], // dec_Whh
        (const float*)d_in[22], // dec_bih
        (const float*)d_in[23]  // dec_bhh
    };

    prep_kernel<<<56, 256, 0, stream>>>(pa, ws);
    enc_mid_kernel<<<128, 512, 0, stream>>>(x_all, Wi_b, Vd_b, Wx_b, ws);
    dec_kernel<<<256, 256, 0, stream>>>(V_w, V_b, reg_w, reg_b, ws, out);
}

// Round 2
// 7118.835 us; speedup vs baseline: 1.2534x; 1.2534x over previous
//
#include <hip/hip_runtime.h>

#define B_   1024
#define TE   168
#define TD   24
#define F_   64
#define H_   128
#define H2_  256
#define G_   512
#define KM_  320   // combined [h|c|x] K for m1

// ---- workspace float offsets ----
#define OFF_WMT    0          // [320][128]  rows 0..255 = We^T, 256..319 = Wi^T
#define OFF_VdT    40960      // [128][64]
#define OFF_eWihT  49152      // [64][512]
#define OFF_eWhhT  81920      // [128][512]
#define OFF_mWihT  147456     // [128][512]
#define OFF_mWhhT  212992     // [128][512]
#define OFF_WxT    278528     // [128][128]
#define OFF_WhT    294912     // [256][128]
#define OFF_dWihT  327680     // [128][512]
#define OFF_dWhhT  393216     // [128][512]
#define OFF_ENCB   458752     // [512] bih+bhh
#define OFF_MIDB   459264
#define OFF_DECB   459776
#define OFF_MID    460800                      // [1024][168][128]
#define OFF_WX     (OFF_MID + B_*TE*H_)        // [1024][168][128]
#define OFF_STH    (OFF_WX  + B_*TE*H_)        // [1024][128]
#define OFF_STC    (OFF_STH + B_*H_)
#define WS_FLOATS  (OFF_STC + B_*H_)

__device__ __forceinline__ float fexp2(float x) { return __builtin_amdgcn_exp2f(x); }
__device__ __forceinline__ float frcp(float x)  { return __builtin_amdgcn_rcpf(x); }
#define LOG2E 1.4426950408889634f

__device__ __forceinline__ float sigm(float x) {
    return frcp(1.f + fexp2(-LOG2E * x));
}
__device__ __forceinline__ float tanh_fast(float x) {
    float e = fexp2(2.f * LOG2E * x);
    return 1.f - 2.f * frcp(e + 1.f);
}

// ---------------- prep: transpose weights to [K][N], sum bias pairs ----------------
struct PrepArgs {
    const float *We, *Wi, *Vd, *eWih, *eWhh, *eBih, *eBhh,
                *mWih, *mWhh, *mBih, *mBhh, *Wx, *Wh, *dWih, *dWhh, *dBih, *dBhh;
};

__global__ void prep_kernel(PrepArgs a, float* __restrict__ ws) {
    int sec  = blockIdx.x >> 2;
    int base = (blockIdx.x & 3) * blockDim.x + threadIdx.x;
    const int stride = blockDim.x * 4;
    const float* src = nullptr; int R = 0, C = 0, off = 0;
    switch (sec) {
        case 0:  src = a.We;   R = 128; C = 256; off = OFF_WMT;           break;
        case 1:  src = a.Wi;   R = 128; C = 64;  off = OFF_WMT + 32768;   break;
        case 2:  src = a.Vd;   R = 64;  C = 128; off = OFF_VdT;   break;
        case 3:  src = a.eWih; R = 512; C = 64;  off = OFF_eWihT; break;
        case 4:  src = a.eWhh; R = 512; C = 128; off = OFF_eWhhT; break;
        case 5:  src = a.mWih; R = 512; C = 128; off = OFF_mWihT; break;
        case 6:  src = a.mWhh; R = 512; C = 128; off = OFF_mWhhT; break;
        case 7:  src = a.Wx;   R = 128; C = 128; off = OFF_WxT;   break;
        case 8:  src = a.Wh;   R = 128; C = 256; off = OFF_WhT;   break;
        case 9:  src = a.dWih; R = 512; C = 128; off = OFF_dWihT; break;
        case 10: src = a.dWhh; R = 512; C = 128; off = OFF_dWhhT; break;
        case 11: for (int i = base; i < 512; i += stride) ws[OFF_ENCB + i] = a.eBih[i] + a.eBhh[i]; return;
        case 12: for (int i = base; i < 512; i += stride) ws[OFF_MIDB + i] = a.mBih[i] + a.mBhh[i]; return;
        case 13: for (int i = base; i < 512; i += stride) ws[OFF_DECB + i] = a.dBih[i] + a.dBhh[i]; return;
        default: return;
    }
    int n = R * C;
    int rmask  = R - 1;
    int rshift = (R == 512) ? 9 : ((R == 128) ? 7 : 6);
    // dst[c*R + r] = src[r*C + c]
    for (int o = base; o < n; o += stride) {
        int r = o & rmask, c = o >> rshift;
        ws[off + o] = src[r * C + c];
    }
}

// ---------------- persistent encoder + mid LSTM: 256 blocks x 512 thr, 4 rows/block ----------------
__global__ __launch_bounds__(512, 1) void enc_mid_kernel(
    const float* __restrict__ x_all,   // [B][Te][F]
    const float* __restrict__ Wi_b,
    const float* __restrict__ Vd_b,
    const float* __restrict__ Wx_b,
    float* __restrict__ ws)
{
    __shared__ float hcx[4][KM_];     // [h | c | x] per row
    __shared__ float hm[4][H_];
    __shared__ float cm[4][H_];
    __shared__ float xin[4][F_];
    __shared__ float av[4][H_];
    __shared__ float avp[4][4][H_];   // [ks][r][j] m1 k-split partials
    __shared__ float gt[4][G_];
    __shared__ float bWi[H_], bVd[F_], bWx[H_];
    __shared__ float bE[G_], bM[G_];

    const int tid = threadIdx.x;
    const int b0  = blockIdx.x * 4;

    for (int i = tid; i < 4 * H2_; i += 512) { int r = i >> 8, c = i & 255; hcx[r][c] = 0.f; }
    for (int i = tid; i < 4 * H_;  i += 512) { ((float*)hm)[i] = 0.f; ((float*)cm)[i] = 0.f; }
    if (tid < H_) { bWi[tid] = Wi_b[tid]; bWx[tid] = Wx_b[tid]; }
    if (tid < F_) bVd[tid] = Vd_b[tid];
    bE[tid & 511] = ws[OFF_ENCB + (tid & 511)];
    bM[tid & 511] = ws[OFF_MIDB + (tid & 511)];
    if (tid < 256) { // x for t=0
        int r = tid >> 6, f = tid & 63;
        hcx[r][H2_ + f] = x_all[((b0 + r) * TE + 0) * F_ + f];
    }
    __syncthreads();

    const float4* WmT4   = (const float4*)(ws + OFF_WMT);     // [320][128]
    const float*  VdT    = ws + OFF_VdT;                      // [128][64]
    const float4* eWihT4 = (const float4*)(ws + OFF_eWihT);   // [64][512]
    const float4* eWhhT4 = (const float4*)(ws + OFF_eWhhT);   // [128][512]
    const float4* mWihT4 = (const float4*)(ws + OFF_mWihT);   // [128][512]
    const float4* mWhhT4 = (const float4*)(ws + OFF_mWhhT);   // [128][512]
    const float*  WxT    = ws + OFF_WxT;                      // [128][128]
    float* mid_out = ws + OFF_MID;
    float* wx_out  = ws + OFF_WX;

    for (int t = 0; t < TE; ++t) {
        // P1: m1 partials  av_part = [h|c|x] @ WmT   (k-split x4 across waves)
        {
            int cg = tid & 31, r = (tid >> 5) & 3, ks = tid >> 7;
            int j0 = cg * 4, k0 = ks * 80;
            float a0 = 0.f, a1 = 0.f, a2 = 0.f, a3 = 0.f;
            #pragma unroll 4
            for (int k = k0; k < k0 + 80; ++k) {
                float4 w = WmT4[k * 32 + cg];
                float hv = hcx[r][k];
                a0 += w.x * hv; a1 += w.y * hv; a2 += w.z * hv; a3 += w.w * hv;
            }
            *(float4*)&avp[ks][r][j0] = make_float4(a0, a1, a2, a3);
        }
        __syncthreads();

        // P2: combine partials + bias + tanh
        {
            int r = tid >> 7, j = tid & 127;
            float v = (avp[0][r][j] + avp[1][r][j]) + (avp[2][r][j] + avp[3][r][j]) + bWi[j];
            av[r][j] = tanh_fast(v);
        }
        __syncthreads();

        // P3: s = av@VdT + bVd; softmax over 64; xin = x * softmax(s)   (one wave per row)
        if (tid < 256) {
            int j = tid & 63, r = tid >> 6;
            float s0 = 0.f, s1 = 0.f, s2 = 0.f, s3 = 0.f;
            #pragma unroll 2
            for (int k = 0; k < H_; k += 4) {
                s0 += VdT[(k    ) * 64 + j] * av[r][k    ];
                s1 += VdT[(k + 1) * 64 + j] * av[r][k + 1];
                s2 += VdT[(k + 2) * 64 + j] * av[r][k + 2];
                s3 += VdT[(k + 3) * 64 + j] * av[r][k + 3];
            }
            float acc = bVd[j] + ((s0 + s1) + (s2 + s3));
            float m = acc;
            for (int off = 32; off > 0; off >>= 1) m = fmaxf(m, __shfl_xor(m, off, 64));
            float e = fexp2((acc - m) * LOG2E);
            float ssum = e;
            for (int off = 32; off > 0; off >>= 1) ssum += __shfl_xor(ssum, off, 64);
            xin[r][j] = hcx[r][H2_ + j] * e * frcp(ssum);
        }
        __syncthreads();

        // P4: enc gates [4][512] = xin@eWihT + h@eWhhT + bE
        {
            int cg = tid & 127, r = tid >> 7;
            int j0 = cg * 4;
            float a0 = bE[j0], a1 = bE[j0+1], a2 = bE[j0+2], a3 = bE[j0+3];
            #pragma unroll 4
            for (int k = 0; k < F_; ++k) {
                float4 w = eWihT4[k * 128 + cg];
                float xv = xin[r][k];
                a0 += w.x * xv; a1 += w.y * xv; a2 += w.z * xv; a3 += w.w * xv;
            }
            #pragma unroll 4
            for (int k = 0; k < H_; ++k) {
                float4 w = eWhhT4[k * 128 + cg];
                float hv = hcx[r][k];
                a0 += w.x * hv; a1 += w.y * hv; a2 += w.z * hv; a3 += w.w * hv;
            }
            *(float4*)&gt[r][j0] = make_float4(a0, a1, a2, a3);
        }
        __syncthreads();

        // P5: enc LSTM cell
        {
            int j = tid & 127, r = tid >> 7;
            float gi = gt[r][j], gf = gt[r][j+128], gg = gt[r][j+256], go = gt[r][j+384];
            float c = sigm(gf) * hcx[r][H_ + j] + sigm(gi) * tanh_fast(gg);
            float h = sigm(go) * tanh_fast(c);
            hcx[r][H_ + j] = c; hcx[r][j] = h;
        }
        __syncthreads();

        // P6: mid gates [4][512] = h_enc@mWihT + h_mid@mWhhT + bM
        {
            int cg = tid & 127, r = tid >> 7;
            int j0 = cg * 4;
            float a0 = bM[j0], a1 = bM[j0+1], a2 = bM[j0+2], a3 = bM[j0+3];
            #pragma unroll 4
            for (int k = 0; k < H_; ++k) {
                float4 w = mWihT4[k * 128 + cg];
                float xv = hcx[r][k];
                a0 += w.x * xv; a1 += w.y * xv; a2 += w.z * xv; a3 += w.w * xv;
            }
            #pragma unroll 4
            for (int k = 0; k < H_; ++k) {
                float4 w = mWhhT4[k * 128 + cg];
                float hv = hm[r][k];
                a0 += w.x * hv; a1 += w.y * hv; a2 += w.z * hv; a3 += w.w * hv;
            }
            *(float4*)&gt[r][j0] = make_float4(a0, a1, a2, a3);
        }
        __syncthreads();

        // P7: mid LSTM cell + store mid_out
        {
            int j = tid & 127, r = tid >> 7;
            float gi = gt[r][j], gf = gt[r][j+128], gg = gt[r][j+256], go = gt[r][j+384];
            float c = sigm(gf) * cm[r][j] + sigm(gi) * tanh_fast(gg);
            float h = sigm(go) * tanh_fast(c);
            cm[r][j] = c; hm[r][j] = h;
            mid_out[((b0 + r) * TE + t) * H_ + j] = h;
        }
        __syncthreads();

        // P8: wx = h_mid@WxT + bWx   + prefetch x for t+1
        {
            int j = tid & 127, r = tid >> 7;
            float s0 = 0.f, s1 = 0.f, s2 = 0.f, s3 = 0.f;
            #pragma unroll 2
            for (int k = 0; k < H_; k += 4) {
                s0 += WxT[(k    ) * H_ + j] * hm[r][k    ];
                s1 += WxT[(k + 1) * H_ + j] * hm[r][k + 1];
                s2 += WxT[(k + 2) * H_ + j] * hm[r][k + 2];
                s3 += WxT[(k + 3) * H_ + j] * hm[r][k + 3];
            }
            wx_out[((b0 + r) * TE + t) * H_ + j] = bWx[j] + ((s0 + s1) + (s2 + s3));
            if (tid < 256 && t + 1 < TE) {
                int rr = tid >> 6, f = tid & 63;
                hcx[rr][H2_ + f] = x_all[((b0 + rr) * TE + (t + 1)) * F_ + f];
            }
        }
        __syncthreads();
    }

    // final mid state -> decoder init
    {
        int j = tid & 127, r = tid >> 7;
        ws[OFF_STH + (b0 + r) * H_ + j] = hm[r][j];
        ws[OFF_STC + (b0 + r) * H_ + j] = cm[r][j];
    }
}

// ---------------- persistent decoder: 256 blocks x 512 thr, 4 rows/block ----------------
__global__ __launch_bounds__(512, 1) void dec_kernel(
    const float* __restrict__ Vw_in,
    const float* __restrict__ Vb_in,
    const float* __restrict__ rw_in,
    const float* __restrict__ rb_in,
    const float* __restrict__ ws,
    float* __restrict__ out)
{
    __shared__ float hc2[4][H2_];      // [hi | ci]
    __shared__ float qv[4][H_];        // q, then reused as dec_in
    __shared__ float sb[4][TE];
    __shared__ float dinp[4][4][H_];   // [ts][r][j]
    __shared__ float gt2[4][G_];
    __shared__ float bD[G_], Vw[H_], rw[H_];

    const int tid = threadIdx.x;
    const int b0  = blockIdx.x * 4;
    const float Vb = Vb_in[0], rb = rb_in[0];

    for (int i = tid; i < 4 * H2_; i += 512) {
        int r = i >> 8, c = i & 255;
        hc2[r][c] = (c < H_) ? ws[OFF_STH + (b0 + r) * H_ + c]
                             : ws[OFF_STC + (b0 + r) * H_ + (c - H_)];
    }
    if (tid < H_) { Vw[tid] = Vw_in[tid]; rw[tid] = rw_in[tid]; }
    bD[tid & 511] = ws[OFF_DECB + (tid & 511)];
    __syncthreads();

    const float*  WhT    = ws + OFF_WhT;                      // [256][128]
    const float4* dWihT4 = (const float4*)(ws + OFF_dWihT);   // [128][512]
    const float4* dWhhT4 = (const float4*)(ws + OFF_dWhhT);   // [128][512]
    const float4* wx4    = (const float4*)(ws + OFF_WX);
    const float4* mid4   = (const float4*)(ws + OFF_MID);

    for (int td = 0; td < TD; ++td) {
        // P1: q = [hi|ci]@WhT  [4][128]
        {
            int j = tid & 127, r = tid >> 7;
            float s0 = 0.f, s1 = 0.f, s2 = 0.f, s3 = 0.f;
            #pragma unroll 4
            for (int k = 0; k < H2_; k += 4) {
                s0 += WhT[(k    ) * H_ + j] * hc2[r][k    ];
                s1 += WhT[(k + 1) * H_ + j] * hc2[r][k + 1];
                s2 += WhT[(k + 2) * H_ + j] * hc2[r][k + 2];
                s3 += WhT[(k + 3) * H_ + j] * hc2[r][k + 3];
            }
            qv[r][j] = (s0 + s1) + (s2 + s3);
        }
        __syncthreads();

        // P2: scores sb[r][tp] = sum_h tanh(q[r][h] + wx[b][tp][h]) * Vw[h] + Vb
        for (int task = tid; task < 4 * TE; task += 512) {
            int r = task & 3, tp = task >> 2;
            const float4* wxr = wx4 + ((size_t)(b0 + r) * TE + tp) * (H_ / 4);
            float acc = Vb;
            #pragma unroll 8
            for (int kk = 0; kk < H_ / 4; ++kk) {
                float4 w = wxr[kk];
                int j = kk * 4;
                acc += tanh_fast(qv[r][j]     + w.x) * Vw[j];
                acc += tanh_fast(qv[r][j + 1] + w.y) * Vw[j + 1];
                acc += tanh_fast(qv[r][j + 2] + w.z) * Vw[j + 2];
                acc += tanh_fast(qv[r][j + 3] + w.w) * Vw[j + 3];
            }
            sb[r][tp] = acc;
        }
        __syncthreads();

        // P3: dec_in partials over tp chunks of 42
        {
            int ts = tid >> 7, r = (tid >> 5) & 3, cg = tid & 31;
            int t0 = ts * 42;
            float4 a = make_float4(0.f, 0.f, 0.f, 0.f);
            #pragma unroll 2
            for (int tp = t0; tp < t0 + 42; ++tp) {
                float s = sb[r][tp];
                float4 m = mid4[((size_t)(b0 + r) * TE + tp) * 32 + cg];
                a.x += s * m.x; a.y += s * m.y; a.z += s * m.z; a.w += s * m.w;
            }
            *(float4*)&dinp[ts][r][cg * 4] = a;
        }
        __syncthreads();
        // P3b: combine into qv (reused as dec_in; q no longer needed)
        {
            int r = tid >> 7, j = tid & 127;
            qv[r][j] = (dinp[0][r][j] + dinp[1][r][j]) + (dinp[2][r][j] + dinp[3][r][j]);
        }
        __syncthreads();

        // P4: gates [4][512] = dec_in@dWihT + hi@dWhhT + bD
        {
            int cg = tid & 127, r = tid >> 7;
            int j0 = cg * 4;
            float a0 = bD[j0], a1 = bD[j0+1], a2 = bD[j0+2], a3 = bD[j0+3];
            #pragma unroll 4
            for (int k = 0; k < H_; ++k) {
                float4 w = dWihT4[k * 128 + cg];
                float xv = qv[r][k];
                a0 += w.x * xv; a1 += w.y * xv; a2 += w.z * xv; a3 += w.w * xv;
            }
            #pragma unroll 4
            for (int k = 0; k < H_; ++k) {
                float4 w = dWhhT4[k * 128 + cg];
                float hv = hc2[r][k];
                a0 += w.x * hv; a1 += w.y * hv; a2 += w.z * hv; a3 += w.w * hv;
            }
            *(float4*)&gt2[r][j0] = make_float4(a0, a1, a2, a3);
        }
        __syncthreads();

        // P5: LSTM update
        {
            int j = tid & 127, r = tid >> 7;
            float gi = gt2[r][j], gf = gt2[r][j+128], gg = gt2[r][j+256], go = gt2[r][j+384];
            float c = sigm(gf) * hc2[r][H_ + j] + sigm(gi) * tanh_fast(gg);
            float h = sigm(go) * tanh_fast(c);
            hc2[r][H_ + j] = c; hc2[r][j] = h;
        }
        __syncthreads();

        // P6: out[b][td] = h . reg_w + reg_b   (one wave per row)
        if (tid < 256) {
            int r = tid >> 6, lane = tid & 63;
            float v = hc2[r][lane] * rw[lane] + hc2[r][lane + 64] * rw[lane + 64];
            for (int off = 32; off > 0; off >>= 1) v += __shfl_xor(v, off, 64);
            if (lane == 0) out[(b0 + r) * TD + td] = v + rb;
        }
        // no barrier needed: next P1 writes qv (already sync'd past P4) and reads hc2 (sync'd at P5)
        __syncthreads();
    }
}

extern "C" void kernel_launch(void* const* d_in, const int* in_sizes, int n_in,
                              void* d_out, int out_size, void* d_ws, size_t ws_size,
                              hipStream_t stream)
{
    (void)in_sizes; (void)n_in; (void)out_size;
    if (ws_size < (size_t)WS_FLOATS * sizeof(float)) return;

    const float* x_all = (const float*)d_in[0];
    const float* Wi_b  = (const float*)d_in[3];
    const float* Vd_b  = (const float*)d_in[6];
    const float* Wx_b  = (const float*)d_in[16];
    const float* V_w   = (const float*)d_in[18];
    const float* V_b   = (const float*)d_in[19];
    const float* reg_w = (const float*)d_in[24];
    const float* reg_b = (const float*)d_in[25];
    float* ws  = (float*)d_ws;
    float* out = (float*)d_out;

    PrepArgs pa{
        (const float*)d_in[4],  // We_w
        (const float*)d_in[2],  // Wi_w
        (const float*)d_in[5],  // Vd_w
        (const float*)d_in[7],  // enc_Wih
        (const float*)d_in[8],  // enc_Whh
        (const float*)d_in[9],  // enc_bih
        (const float*)d_in[10], // enc_bhh
        (const float*)d_in[11], // mid_Wih
        (const float*)d_in[12], // mid_Whh
        (const float*)d_in[13], // mid_bih
        (const float*)d_in[14], // mid_bhh
        (const float*)d_in[15], // Wx_w
        (const float*)d_in[17], // Wh_w
        (const float*)d_in[20], // dec_Wih
        (const float*)d_in[21], // dec_Whh
        (const float*)d_in[22], // dec_bih
        (const float*)d_in[23]  // dec_bhh
    };

    prep_kernel<<<56, 256, 0, stream>>>(pa, ws);
    enc_mid_kernel<<<256, 512, 0, stream>>>(x_all, Wi_b, Vd_b, Wx_b, ws);
    dec_kernel<<<256, 512, 0, stream>>>(V_w, V_b, reg_w, reg_b, ws, out);
}